// Round 13
// baseline (488.225 us; speedup 1.0000x reference)
//
#include <hip/hip_runtime.h>
#include <hip/hip_bf16.h>

// GPT2 symmetric latent attention, MI355X (gfx950)
// B=4 T=2048 C=1024 H=16 R=64 head_dim=64
//
// Pipeline:
//  1. cvt f32->bf16: hs, basis_w, v_w, o_w
//  2. head_mats (pre-scaled by 0.125*log2e): hmT[h][s][r]
//  3. latent = hs @ basis^T            (MFMA NT gemm, 8192x64, K=1024)
//  4. vT     = (hs @ v_w^T + v_b)^T    ([B,H,64,T] bf16, 128x128 tile)
//  5. lt     = latent @ hmT^T batched  (pre-scaled scores in log2 domain)
//  6. flash attention v4: 32 q-rows/wave, split-K x2 (even/odd k-tiles) with
//     in-block LDS merge; 8-wave blocks, 4096 waves (4/SIMD), barrier-free
//     inner loop, defer-max, truncating P-convert
//  7. out    = y @ o_w^T + o_b (f32, 128x128 tile)

#define N_HEAD 16
#define RANK 64

typedef __attribute__((ext_vector_type(8))) short bf16x8;
typedef __attribute__((ext_vector_type(4))) float f32x4;

__device__ __forceinline__ ushort f2b(float f) {
    // round-to-nearest-even f32 -> bf16
    unsigned u = __builtin_bit_cast(unsigned, f);
    u += 0x7fffu + ((u >> 16) & 1u);
    return (ushort)(u >> 16);
}

__device__ __forceinline__ ushort f2b_trunc(float f) {
    // truncating f32 -> bf16 (1 VALU op); P in [0, 2^11.5], bias ~0.2% ok
    return (ushort)(__builtin_bit_cast(unsigned, f) >> 16);
}

// LDS swizzle for [R][64]-ushort tiles: col ^ ((row&7)<<3); conflict-free column reads.
__device__ __forceinline__ int swz(int row, int col) {
    return (row << 6) | (col ^ ((row & 7) << 3));
}

__global__ void cvt_kernel(const float* __restrict__ src, ushort* __restrict__ dst, int n4) {
    int i = blockIdx.x * blockDim.x + threadIdx.x;
    if (i >= n4) return;
    float4 v = ((const float4*)src)[i];
    ushort4 o;
    o.x = f2b(v.x); o.y = f2b(v.y); o.z = f2b(v.z); o.w = f2b(v.w);
    ((ushort4*)dst)[i] = o;
}

// hmT[h][s][r] = SCLF * (core_sym[r][s]/H + resid[h][r][s] - mean_h resid[.][r][s])
// SCLF = 1/sqrt(R) * log2(e): scores leave the lt-GEMM pre-scaled in log2 domain.
__global__ void headmats_kernel(const float* __restrict__ core,
                                const float* __restrict__ resid,
                                ushort* __restrict__ hmT) {
    const float SCLF = 0.125f * 1.44269504089f;
    int idx = blockIdx.x * 256 + threadIdx.x;
    if (idx >= RANK * RANK) return;
    int r = idx >> 6, s = idx & 63;
    float mean = 0.f;
    for (int h = 0; h < N_HEAD; ++h) mean += resid[h * RANK * RANK + idx];
    mean *= (1.0f / N_HEAD);
    float cs = 0.5f * (core[r * RANK + s] + core[s * RANK + r]) * (1.0f / N_HEAD);
    for (int h = 0; h < N_HEAD; ++h) {
        float val = (cs + resid[h * RANK * RANK + idx] - mean) * SCLF;
        hmT[h * RANK * RANK + s * RANK + r] = f2b(val);
    }
}

// Generic NT GEMM: C[m,n] = sum_k A[m,k] * W[n,k] (+bias[n]).
// 128 x BN tile, BK=64, 4 waves (2x2), wave owns 64 x BN/2.
// Batched via blockIdx.z. outVT=1: write bf16 transposed as vT[b*1024+col][t] (T=2048).
template<int BN>
__global__ __launch_bounds__(256) void gemm_nt(
    const ushort* __restrict__ A, const ushort* __restrict__ W,
    const float* __restrict__ bias,
    float* __restrict__ outF, ushort* __restrict__ outB,
    int M, int N, int K,
    int zDivA, long long aStride, int zModW, long long wStride, long long oStride,
    int outVT)
{
    constexpr int FN = BN / 32;
    __shared__ ushort As[128 * 72];
    __shared__ ushort Ws[BN * 72];

    int z = blockIdx.z;
    A += (size_t)(z / zDivA) * aStride;
    W += (size_t)(z % zModW) * wStride;
    size_t obase = (size_t)z * oStride;

    int m0 = blockIdx.y * 128;
    int n0 = blockIdx.x * BN;
    int t = threadIdx.x;
    int wave = t >> 6, lane = t & 63;
    int wr = wave >> 1, wc = wave & 1;
    int g = lane >> 4, ln = lane & 15;

    f32x4 acc[4][FN];
    for (int i = 0; i < 4; ++i)
        for (int j = 0; j < FN; ++j) acc[i][j] = (f32x4){0.f, 0.f, 0.f, 0.f};

    for (int k0 = 0; k0 < K; k0 += 64) {
        for (int q = 0; q < 4; ++q) {
            int e = (t + 256 * q) * 8;
            int row = e >> 6, col = e & 63;
            *(bf16x8*)&As[row * 72 + col] =
                *(const bf16x8*)(A + (size_t)(m0 + row) * K + k0 + col);
        }
        for (int q = 0; q < BN / 32; ++q) {
            int e = (t + 256 * q) * 8;
            int row = e >> 6, col = e & 63;
            *(bf16x8*)&Ws[row * 72 + col] =
                *(const bf16x8*)(W + (size_t)(n0 + row) * K + k0 + col);
        }
        __syncthreads();
        for (int ks = 0; ks < 2; ++ks) {
            bf16x8 a[4], b[FN];
            for (int fm = 0; fm < 4; ++fm)
                a[fm] = *(const bf16x8*)&As[(wr * 64 + fm * 16 + ln) * 72 + ks * 32 + 8 * g];
            for (int fn = 0; fn < FN; ++fn)
                b[fn] = *(const bf16x8*)&Ws[(wc * (BN / 2) + fn * 16 + ln) * 72 + ks * 32 + 8 * g];
            for (int fm = 0; fm < 4; ++fm)
                for (int fn = 0; fn < FN; ++fn)
                    acc[fm][fn] = __builtin_amdgcn_mfma_f32_16x16x32_bf16(
                        a[fm], b[fn], acc[fm][fn], 0, 0, 0);
        }
        __syncthreads();
    }

    // C/D layout: col=lane&15, row=4*(lane>>4)+reg  [measured m89/m91]
    if (outVT) {
        for (int fm = 0; fm < 4; ++fm)
            for (int fn = 0; fn < FN; ++fn) {
                int row = m0 + wr * 64 + fm * 16 + 4 * g;
                int col = n0 + wc * (BN / 2) + fn * 16 + ln;
                float bv = bias ? bias[col] : 0.f;
                ushort4 us;
                us.x = f2b(acc[fm][fn][0] + bv);
                us.y = f2b(acc[fm][fn][1] + bv);
                us.z = f2b(acc[fm][fn][2] + bv);
                us.w = f2b(acc[fm][fn][3] + bv);
                size_t off = ((size_t)(row >> 11) * 1024 + col) * 2048 + (row & 2047);
                *(ushort4*)(outB + off) = us;
            }
    } else {
        for (int fm = 0; fm < 4; ++fm)
            for (int fn = 0; fn < FN; ++fn)
                for (int r = 0; r < 4; ++r) {
                    int row = m0 + wr * 64 + fm * 16 + 4 * g + r;
                    int col = n0 + wc * (BN / 2) + fn * 16 + ln;
                    float val = acc[fm][fn][r];
                    if (bias) val += bias[col];
                    size_t o = obase + (size_t)row * N + col;
                    if (outF) outF[o] = val;
                    if (outB) outB[o] = f2b(val);
                }
    }
}

// Flash attention v4: grid (8, H, B), 512 thr = 8 waves = 4 split-K pairs.
// Wave w: rows [qt*128 + (w>>1)*32, +32), k-tiles kt = (w&1), (w&1)+2, ...
// Each (q-row, k-tile) computed exactly once -> no extra K/V traffic vs R7.
// Partials merged in-block via LDS (one barrier per pass).
__global__ __launch_bounds__(512, 4) void attn_kernel(
    const ushort* __restrict__ lt, const ushort* __restrict__ latent,
    const ushort* __restrict__ vT, ushort* __restrict__ y)
{
    const int T = 2048, C = 1024;
    __shared__ ushort Ps[8][32 * 64];          // per-wave P, swizzled (32 KB)
    __shared__ float Oex[4][64][36];           // per-pair partner O: [d][row+pad] (36 KB)
    __shared__ float Mex[4][32], Lex[4][32];   // per-pair partner m, l (1 KB)

    int pq = blockIdx.x, h = blockIdx.y, b = blockIdx.z;
    int t = threadIdx.x, w = t >> 6, lane = t & 63;
    int g = lane >> 4, ln = lane & 15;
    int hf = w >> 1, par = w & 1;

    const ushort* Kg = latent + (size_t)b * T * RANK;
    const ushort* Vg = vT + (size_t)(b * N_HEAD + h) * 64 * T;
    ushort* Pw = Ps[w];
    const float THR = 11.5f;   // defer-max threshold (log2 domain)

    for (int pass = 0; pass < 2; ++pass) {
        int qt = pass ? (15 - pq) : pq;
        int qrow0 = qt * 128 + hf * 32;

        const ushort* Qg = lt + ((size_t)(b * N_HEAD + h) * T + qrow0) * RANK;
        bf16x8 qa[2][2];
        for (int m = 0; m < 2; ++m)
            for (int ks = 0; ks < 2; ++ks)
                qa[m][ks] = *(const bf16x8*)(Qg + (size_t)(m * 16 + ln) * RANK + ks * 32 + 8 * g);

        float mr[2][4], lp[2][4];
        f32x4 o[2][4];
        for (int m = 0; m < 2; ++m)
            for (int r = 0; r < 4; ++r) { mr[m][r] = -INFINITY; lp[m][r] = 0.f; }
        for (int m = 0; m < 2; ++m)
            for (int fn = 0; fn < 4; ++fn) o[m][fn] = (f32x4){0.f, 0.f, 0.f, 0.f};

        int kmax = 2 * qt + (hf >> 1);   // last k-tile this wave's rows need
        for (int kt = par; kt <= kmax; kt += 2) {
            // S = Q @ K^T (32 x 64), K fragments straight from global (L2-hot)
            f32x4 s[2][4];
            for (int m = 0; m < 2; ++m)
                for (int fn = 0; fn < 4; ++fn) s[m][fn] = (f32x4){0.f, 0.f, 0.f, 0.f};
            for (int ks = 0; ks < 2; ++ks) {
                bf16x8 kb[4];
                for (int fn = 0; fn < 4; ++fn)
                    kb[fn] = *(const bf16x8*)(Kg +
                        (size_t)(kt * 64 + fn * 16 + ln) * RANK + ks * 32 + 8 * g);
                for (int m = 0; m < 2; ++m)
                    for (int fn = 0; fn < 4; ++fn)
                        s[m][fn] = __builtin_amdgcn_mfma_f32_16x16x32_bf16(
                            qa[m][ks], kb[fn], s[m][fn], 0, 0, 0);
            }

            // causal mask (diagonal tiles only) + per-lane partial row max
            float rm[2][4];
            for (int m = 0; m < 2; ++m) {
                for (int r = 0; r < 4; ++r) rm[m][r] = -INFINITY;
                int qb = qrow0 + m * 16 + 4 * g;
                if (kt * 64 + 63 > qrow0 + m * 16) {   // wave-uniform branch
                    for (int fn = 0; fn < 4; ++fn) {
                        int key = kt * 64 + fn * 16 + ln;
                        for (int r = 0; r < 4; ++r) {
                            float sv = s[m][fn][r];
                            if (key > qb + r) sv = -INFINITY;
                            s[m][fn][r] = sv;
                            rm[m][r] = fmaxf(rm[m][r], sv);
                        }
                    }
                } else {
                    for (int fn = 0; fn < 4; ++fn)
                        for (int r = 0; r < 4; ++r)
                            rm[m][r] = fmaxf(rm[m][r], s[m][fn][r]);
                }
            }

            // defer-max on UNREDUCED maxima: common path has zero shuffles
            int need = 0;
            for (int m = 0; m < 2; ++m)
                for (int r = 0; r < 4; ++r) need |= (rm[m][r] > mr[m][r] + THR);
            if (__any(need)) {
                for (int off = 1; off < 16; off <<= 1)
                    for (int m = 0; m < 2; ++m)
                        for (int r = 0; r < 4; ++r)
                            rm[m][r] = fmaxf(rm[m][r], __shfl_xor(rm[m][r], off));
                for (int m = 0; m < 2; ++m)
                    for (int r = 0; r < 4; ++r) {
                        float nm = fmaxf(mr[m][r], rm[m][r]);
                        float al = exp2f(mr[m][r] - nm);   // uniform in 16-lane group
                        mr[m][r] = nm;
                        lp[m][r] *= al;
                        for (int fn = 0; fn < 4; ++fn) o[m][fn][r] *= al;
                    }
            }

            // P = exp2(s - m); per-lane partial sums; truncating bf16 store
            for (int m = 0; m < 2; ++m)
                for (int fn = 0; fn < 4; ++fn)
                    for (int r = 0; r < 4; ++r) {
                        float p = exp2f(s[m][fn][r] - mr[m][r]);
                        lp[m][r] += p;
                        Pw[swz(m * 16 + 4 * g + r, fn * 16 + ln)] = f2b_trunc(p);
                    }

            // O += P @ V (P via wave-private LDS; same-wave dep via lgkmcnt)
            for (int ks = 0; ks < 2; ++ks) {
                bf16x8 pa[2];
                for (int m = 0; m < 2; ++m)
                    pa[m] = *(const bf16x8*)&Pw[swz(m * 16 + ln, ks * 32 + 8 * g)];
                for (int fn = 0; fn < 4; ++fn) {
                    bf16x8 vb = *(const bf16x8*)(Vg +
                        (size_t)(fn * 16 + ln) * T + kt * 64 + ks * 32 + 8 * g);
                    for (int m = 0; m < 2; ++m)
                        o[m][fn] = __builtin_amdgcn_mfma_f32_16x16x32_bf16(
                            pa[m], vb, o[m][fn], 0, 0, 0);
                }
            }
        }

        // reduce per-lane row sums across the 16-lane group
        for (int off = 1; off < 16; off <<= 1)
            for (int m = 0; m < 2; ++m)
                for (int r = 0; r < 4; ++r) lp[m][r] += __shfl_xor(lp[m][r], off);

        // odd wave exports its partial (O, m, l) to LDS
        if (par) {
            for (int m = 0; m < 2; ++m)
                for (int fn = 0; fn < 4; ++fn)
                    *(f32x4*)&Oex[hf][fn * 16 + ln][m * 16 + 4 * g] = o[m][fn];
            if (ln == 0)
                for (int m = 0; m < 2; ++m)
                    for (int r = 0; r < 4; ++r) {
                        Mex[hf][m * 16 + 4 * g + r] = mr[m][r];
                        Lex[hf][m * 16 + 4 * g + r] = lp[m][r];
                    }
        }
        __syncthreads();

        // even wave merges the two partials and writes y
        if (!par) {
            for (int m = 0; m < 2; ++m) {
                float a0[4], sc1[4], li[4];
                for (int r = 0; r < 4; ++r) {
                    int row = m * 16 + 4 * g + r;
                    float mo = Mex[hf][row], lo = Lex[hf][row];
                    float Mx = fmaxf(mr[m][r], mo);
                    a0[r] = exp2f(mr[m][r] - Mx);
                    sc1[r] = exp2f(mo - Mx);
                    li[r] = 1.0f / (lp[m][r] * a0[r] + lo * sc1[r]);
                }
                for (int fn = 0; fn < 4; ++fn) {
                    f32x4 Oo = *(const f32x4*)&Oex[hf][fn * 16 + ln][m * 16 + 4 * g];
                    for (int r = 0; r < 4; ++r) {
                        int row = qrow0 + m * 16 + 4 * g + r;
                        float val = (o[m][fn][r] * a0[r] + Oo[r] * sc1[r]) * li[r];
                        y[((size_t)b * T + row) * C + h * 64 + fn * 16 + ln] = f2b(val);
                    }
                }
            }
        }
        __syncthreads();   // protect exchange buffers before next pass overwrites
    }
}

extern "C" void kernel_launch(void* const* d_in, const int* in_sizes, int n_in,
                              void* d_out, int out_size, void* d_ws, size_t ws_size,
                              hipStream_t stream) {
    const float* hs    = (const float*)d_in[0];
    const float* basis = (const float*)d_in[1];
    const float* core  = (const float*)d_in[2];
    const float* resid = (const float*)d_in[3];
    const float* v_w   = (const float*)d_in[4];
    const float* v_b   = (const float*)d_in[5];
    const float* o_w   = (const float*)d_in[6];
    const float* o_b   = (const float*)d_in[7];
    float* out = (float*)d_out;

    const int B = 4, T = 2048, C = 1024, H = N_HEAD, R = RANK;
    const int M = B * T;  // 8192

    char* ws = (char*)d_ws;
    ushort* hs_b    = (ushort*)(ws + 0);         // 16,777,216 B
    ushort* y_b     = hs_b;                      // alias: hs dead after v-gemm
    ushort* basis_b = (ushort*)(ws + 16777216);  // 131,072
    ushort* vw_b    = (ushort*)(ws + 16908288);  // 2,097,152
    ushort* ow_b    = (ushort*)(ws + 19005440);  // 2,097,152
    ushort* hm_b    = (ushort*)(ws + 21102592);  // 131,072
    ushort* lat_b   = (ushort*)(ws + 21233664);  // 1,048,576
    ushort* lt_b    = (ushort*)(ws + 22282240);  // 16,777,216
    ushort* vT_b    = (ushort*)(ws + 39059456);  // 16,777,216  [B,H,64,T]

    // 1. convert inputs to bf16
    cvt_kernel<<<dim3(M * C / 4 / 256), 256, 0, stream>>>(hs, hs_b, M * C / 4);
    cvt_kernel<<<dim3(R * C / 4 / 256), 256, 0, stream>>>(basis, basis_b, R * C / 4);
    cvt_kernel<<<dim3(C * C / 4 / 256), 256, 0, stream>>>(v_w, vw_b, C * C / 4);
    cvt_kernel<<<dim3(C * C / 4 / 256), 256, 0, stream>>>(o_w, ow_b, C * C / 4);

    // 2. head matrices (transposed, pre-scaled, bf16)
    headmats_kernel<<<dim3(16), 256, 0, stream>>>(core, resid, hm_b);

    // 3. latent = hs @ basis^T : [8192,64]
    gemm_nt<64><<<dim3(1, M / 128, 1), 256, 0, stream>>>(
        hs_b, basis_b, nullptr, nullptr, lat_b, M, R, C, 1, 0, 1, 0, 0, 0);

    // 4. vT = (hs @ v_w^T + v_b)^T : [B,H,64,T] bf16, 128x128 tile
    gemm_nt<128><<<dim3(C / 128, M / 128, 1), 256, 0, stream>>>(
        hs_b, vw_b, v_b, nullptr, vT_b, M, C, C, 1, 0, 1, 0, 0, 1);

    // 5. lt[b,h] = latent[b] @ hmT[h]^T : batched z = b*H+h (pre-scaled)
    gemm_nt<64><<<dim3(1, T / 128, B * H), 256, 0, stream>>>(
        lat_b, hm_b, nullptr, nullptr, lt_b, T, R, R,
        H, (long long)T * R, H, (long long)R * R, (long long)T * R, 0);

    // 6. flash attention v4 -> y bf16 [B,T,C]
    attn_kernel<<<dim3(8, H, B), 512, 0, stream>>>(lt_b, lat_b, vT_b, y_b);

    // 7. out = y @ o_w^T + o_b : f32, 128x128 tile
    gemm_nt<128><<<dim3(C / 128, M / 128, 1), 256, 0, stream>>>(
        y_b, ow_b, o_b, out, nullptr, M, C, C, 1, 0, 1, 0, 0, 0);
}

// Round 14
// 343.380 us; speedup vs baseline: 1.4218x; 1.4218x over previous
//
#include <hip/hip_runtime.h>
#include <hip/hip_bf16.h>

// GPT2 symmetric latent attention, MI355X (gfx950)
// B=4 T=2048 C=1024 H=16 R=64 head_dim=64
//
// Pipeline:
//  1. cvt f32->bf16: hs, basis_w, v_w, o_w
//  2. head_mats (pre-scaled by 0.125*log2e): hmT[h][s][r]
//  3. latent = hs @ basis^T            (MFMA NT gemm, 8192x64, K=1024)
//  4. vT     = (hs @ v_w^T + v_b)^T    ([B,H,64,T] bf16, 128x128 tile)
//  5. lt     = latent @ hmT^T batched  (pre-scaled scores in log2 domain)
//  6. flash attention v4b: as v4 but NO min-waves cap (R13: __launch_bounds__(512,4)
//     forced VGPR=64 -> inner-loop scratch spill, FETCH 471MB. Natural alloc ~150 VGPR
//     = 3 waves/SIMD, zero spill.)
//  7. out    = y @ o_w^T + o_b (f32, 128x128 tile)

#define N_HEAD 16
#define RANK 64

typedef __attribute__((ext_vector_type(8))) short bf16x8;
typedef __attribute__((ext_vector_type(4))) float f32x4;

__device__ __forceinline__ ushort f2b(float f) {
    // round-to-nearest-even f32 -> bf16
    unsigned u = __builtin_bit_cast(unsigned, f);
    u += 0x7fffu + ((u >> 16) & 1u);
    return (ushort)(u >> 16);
}

__device__ __forceinline__ ushort f2b_trunc(float f) {
    // truncating f32 -> bf16 (1 VALU op); P in [0, 2^11.5], bias ~0.2% ok
    return (ushort)(__builtin_bit_cast(unsigned, f) >> 16);
}

// LDS swizzle for [R][64]-ushort tiles: col ^ ((row&7)<<3); conflict-free column reads.
__device__ __forceinline__ int swz(int row, int col) {
    return (row << 6) | (col ^ ((row & 7) << 3));
}

__global__ void cvt_kernel(const float* __restrict__ src, ushort* __restrict__ dst, int n4) {
    int i = blockIdx.x * blockDim.x + threadIdx.x;
    if (i >= n4) return;
    float4 v = ((const float4*)src)[i];
    ushort4 o;
    o.x = f2b(v.x); o.y = f2b(v.y); o.z = f2b(v.z); o.w = f2b(v.w);
    ((ushort4*)dst)[i] = o;
}

// hmT[h][s][r] = SCLF * (core_sym[r][s]/H + resid[h][r][s] - mean_h resid[.][r][s])
// SCLF = 1/sqrt(R) * log2(e): scores leave the lt-GEMM pre-scaled in log2 domain.
__global__ void headmats_kernel(const float* __restrict__ core,
                                const float* __restrict__ resid,
                                ushort* __restrict__ hmT) {
    const float SCLF = 0.125f * 1.44269504089f;
    int idx = blockIdx.x * 256 + threadIdx.x;
    if (idx >= RANK * RANK) return;
    int r = idx >> 6, s = idx & 63;
    float mean = 0.f;
    for (int h = 0; h < N_HEAD; ++h) mean += resid[h * RANK * RANK + idx];
    mean *= (1.0f / N_HEAD);
    float cs = 0.5f * (core[r * RANK + s] + core[s * RANK + r]) * (1.0f / N_HEAD);
    for (int h = 0; h < N_HEAD; ++h) {
        float val = (cs + resid[h * RANK * RANK + idx] - mean) * SCLF;
        hmT[h * RANK * RANK + s * RANK + r] = f2b(val);
    }
}

// Generic NT GEMM: C[m,n] = sum_k A[m,k] * W[n,k] (+bias[n]).
// 128 x BN tile, BK=64, 4 waves (2x2), wave owns 64 x BN/2.
// Batched via blockIdx.z. outVT=1: write bf16 transposed as vT[b*1024+col][t] (T=2048).
template<int BN>
__global__ __launch_bounds__(256) void gemm_nt(
    const ushort* __restrict__ A, const ushort* __restrict__ W,
    const float* __restrict__ bias,
    float* __restrict__ outF, ushort* __restrict__ outB,
    int M, int N, int K,
    int zDivA, long long aStride, int zModW, long long wStride, long long oStride,
    int outVT)
{
    constexpr int FN = BN / 32;
    __shared__ ushort As[128 * 72];
    __shared__ ushort Ws[BN * 72];

    int z = blockIdx.z;
    A += (size_t)(z / zDivA) * aStride;
    W += (size_t)(z % zModW) * wStride;
    size_t obase = (size_t)z * oStride;

    int m0 = blockIdx.y * 128;
    int n0 = blockIdx.x * BN;
    int t = threadIdx.x;
    int wave = t >> 6, lane = t & 63;
    int wr = wave >> 1, wc = wave & 1;
    int g = lane >> 4, ln = lane & 15;

    f32x4 acc[4][FN];
    for (int i = 0; i < 4; ++i)
        for (int j = 0; j < FN; ++j) acc[i][j] = (f32x4){0.f, 0.f, 0.f, 0.f};

    for (int k0 = 0; k0 < K; k0 += 64) {
        for (int q = 0; q < 4; ++q) {
            int e = (t + 256 * q) * 8;
            int row = e >> 6, col = e & 63;
            *(bf16x8*)&As[row * 72 + col] =
                *(const bf16x8*)(A + (size_t)(m0 + row) * K + k0 + col);
        }
        for (int q = 0; q < BN / 32; ++q) {
            int e = (t + 256 * q) * 8;
            int row = e >> 6, col = e & 63;
            *(bf16x8*)&Ws[row * 72 + col] =
                *(const bf16x8*)(W + (size_t)(n0 + row) * K + k0 + col);
        }
        __syncthreads();
        for (int ks = 0; ks < 2; ++ks) {
            bf16x8 a[4], b[FN];
            for (int fm = 0; fm < 4; ++fm)
                a[fm] = *(const bf16x8*)&As[(wr * 64 + fm * 16 + ln) * 72 + ks * 32 + 8 * g];
            for (int fn = 0; fn < FN; ++fn)
                b[fn] = *(const bf16x8*)&Ws[(wc * (BN / 2) + fn * 16 + ln) * 72 + ks * 32 + 8 * g];
            for (int fm = 0; fm < 4; ++fm)
                for (int fn = 0; fn < FN; ++fn)
                    acc[fm][fn] = __builtin_amdgcn_mfma_f32_16x16x32_bf16(
                        a[fm], b[fn], acc[fm][fn], 0, 0, 0);
        }
        __syncthreads();
    }

    // C/D layout: col=lane&15, row=4*(lane>>4)+reg  [measured m89/m91]
    if (outVT) {
        for (int fm = 0; fm < 4; ++fm)
            for (int fn = 0; fn < FN; ++fn) {
                int row = m0 + wr * 64 + fm * 16 + 4 * g;
                int col = n0 + wc * (BN / 2) + fn * 16 + ln;
                float bv = bias ? bias[col] : 0.f;
                ushort4 us;
                us.x = f2b(acc[fm][fn][0] + bv);
                us.y = f2b(acc[fm][fn][1] + bv);
                us.z = f2b(acc[fm][fn][2] + bv);
                us.w = f2b(acc[fm][fn][3] + bv);
                size_t off = ((size_t)(row >> 11) * 1024 + col) * 2048 + (row & 2047);
                *(ushort4*)(outB + off) = us;
            }
    } else {
        for (int fm = 0; fm < 4; ++fm)
            for (int fn = 0; fn < FN; ++fn)
                for (int r = 0; r < 4; ++r) {
                    int row = m0 + wr * 64 + fm * 16 + 4 * g + r;
                    int col = n0 + wc * (BN / 2) + fn * 16 + ln;
                    float val = acc[fm][fn][r];
                    if (bias) val += bias[col];
                    size_t o = obase + (size_t)row * N + col;
                    if (outF) outF[o] = val;
                    if (outB) outB[o] = f2b(val);
                }
    }
}

// Flash attention v4b: grid (8, H, B), 512 thr = 8 waves = 4 split-K pairs.
// Wave w: rows [qt*128 + (w>>1)*32, +32), k-tiles kt = (w&1), (w&1)+2, ...
// Each (q-row, k-tile) computed exactly once -> no extra K/V traffic vs R7.
// Partials merged in-block via LDS (one barrier per pass).
// NO min-waves cap: natural VGPR (~150) avoids the R13 spill (VGPR=64, 471MB scratch).
__global__ __launch_bounds__(512) void attn_kernel(
    const ushort* __restrict__ lt, const ushort* __restrict__ latent,
    const ushort* __restrict__ vT, ushort* __restrict__ y)
{
    const int T = 2048, C = 1024;
    __shared__ ushort Ps[8][32 * 64];          // per-wave P, swizzled (32 KB)
    __shared__ float Oex[4][64][36];           // per-pair partner O: [d][row+pad] (36 KB)
    __shared__ float Mex[4][32], Lex[4][32];   // per-pair partner m, l (1 KB)

    int pq = blockIdx.x, h = blockIdx.y, b = blockIdx.z;
    int t = threadIdx.x, w = t >> 6, lane = t & 63;
    int g = lane >> 4, ln = lane & 15;
    int hf = w >> 1, par = w & 1;

    const ushort* Kg = latent + (size_t)b * T * RANK;
    const ushort* Vg = vT + (size_t)(b * N_HEAD + h) * 64 * T;
    ushort* Pw = Ps[w];
    const float THR = 11.5f;   // defer-max threshold (log2 domain)

    for (int pass = 0; pass < 2; ++pass) {
        int qt = pass ? (15 - pq) : pq;
        int qrow0 = qt * 128 + hf * 32;

        const ushort* Qg = lt + ((size_t)(b * N_HEAD + h) * T + qrow0) * RANK;
        bf16x8 qa[2][2];
        for (int m = 0; m < 2; ++m)
            for (int ks = 0; ks < 2; ++ks)
                qa[m][ks] = *(const bf16x8*)(Qg + (size_t)(m * 16 + ln) * RANK + ks * 32 + 8 * g);

        float mr[2][4], lp[2][4];
        f32x4 o[2][4];
        for (int m = 0; m < 2; ++m)
            for (int r = 0; r < 4; ++r) { mr[m][r] = -INFINITY; lp[m][r] = 0.f; }
        for (int m = 0; m < 2; ++m)
            for (int fn = 0; fn < 4; ++fn) o[m][fn] = (f32x4){0.f, 0.f, 0.f, 0.f};

        int kmax = 2 * qt + (hf >> 1);   // last k-tile this wave's rows need
        for (int kt = par; kt <= kmax; kt += 2) {
            // S = Q @ K^T (32 x 64), K fragments straight from global (L2-hot)
            f32x4 s[2][4];
            for (int m = 0; m < 2; ++m)
                for (int fn = 0; fn < 4; ++fn) s[m][fn] = (f32x4){0.f, 0.f, 0.f, 0.f};
            for (int ks = 0; ks < 2; ++ks) {
                bf16x8 kb[4];
                for (int fn = 0; fn < 4; ++fn)
                    kb[fn] = *(const bf16x8*)(Kg +
                        (size_t)(kt * 64 + fn * 16 + ln) * RANK + ks * 32 + 8 * g);
                for (int m = 0; m < 2; ++m)
                    for (int fn = 0; fn < 4; ++fn)
                        s[m][fn] = __builtin_amdgcn_mfma_f32_16x16x32_bf16(
                            qa[m][ks], kb[fn], s[m][fn], 0, 0, 0);
            }

            // causal mask (diagonal tiles only) + per-lane partial row max
            float rm[2][4];
            for (int m = 0; m < 2; ++m) {
                for (int r = 0; r < 4; ++r) rm[m][r] = -INFINITY;
                int qb = qrow0 + m * 16 + 4 * g;
                if (kt * 64 + 63 > qrow0 + m * 16) {   // wave-uniform branch
                    for (int fn = 0; fn < 4; ++fn) {
                        int key = kt * 64 + fn * 16 + ln;
                        for (int r = 0; r < 4; ++r) {
                            float sv = s[m][fn][r];
                            if (key > qb + r) sv = -INFINITY;
                            s[m][fn][r] = sv;
                            rm[m][r] = fmaxf(rm[m][r], sv);
                        }
                    }
                } else {
                    for (int fn = 0; fn < 4; ++fn)
                        for (int r = 0; r < 4; ++r)
                            rm[m][r] = fmaxf(rm[m][r], s[m][fn][r]);
                }
            }

            // defer-max on UNREDUCED maxima: common path has zero shuffles
            int need = 0;
            for (int m = 0; m < 2; ++m)
                for (int r = 0; r < 4; ++r) need |= (rm[m][r] > mr[m][r] + THR);
            if (__any(need)) {
                for (int off = 1; off < 16; off <<= 1)
                    for (int m = 0; m < 2; ++m)
                        for (int r = 0; r < 4; ++r)
                            rm[m][r] = fmaxf(rm[m][r], __shfl_xor(rm[m][r], off));
                for (int m = 0; m < 2; ++m)
                    for (int r = 0; r < 4; ++r) {
                        float nm = fmaxf(mr[m][r], rm[m][r]);
                        float al = exp2f(mr[m][r] - nm);   // uniform in 16-lane group
                        mr[m][r] = nm;
                        lp[m][r] *= al;
                        for (int fn = 0; fn < 4; ++fn) o[m][fn][r] *= al;
                    }
            }

            // P = exp2(s - m); per-lane partial sums; truncating bf16 store
            for (int m = 0; m < 2; ++m)
                for (int fn = 0; fn < 4; ++fn)
                    for (int r = 0; r < 4; ++r) {
                        float p = exp2f(s[m][fn][r] - mr[m][r]);
                        lp[m][r] += p;
                        Pw[swz(m * 16 + 4 * g + r, fn * 16 + ln)] = f2b_trunc(p);
                    }

            // O += P @ V (P via wave-private LDS; same-wave dep via lgkmcnt)
            for (int ks = 0; ks < 2; ++ks) {
                bf16x8 pa[2];
                for (int m = 0; m < 2; ++m)
                    pa[m] = *(const bf16x8*)&Pw[swz(m * 16 + ln, ks * 32 + 8 * g)];
                for (int fn = 0; fn < 4; ++fn) {
                    bf16x8 vb = *(const bf16x8*)(Vg +
                        (size_t)(fn * 16 + ln) * T + kt * 64 + ks * 32 + 8 * g);
                    for (int m = 0; m < 2; ++m)
                        o[m][fn] = __builtin_amdgcn_mfma_f32_16x16x32_bf16(
                            pa[m], vb, o[m][fn], 0, 0, 0);
                }
            }
        }

        // reduce per-lane row sums across the 16-lane group
        for (int off = 1; off < 16; off <<= 1)
            for (int m = 0; m < 2; ++m)
                for (int r = 0; r < 4; ++r) lp[m][r] += __shfl_xor(lp[m][r], off);

        // odd wave exports its partial (O, m, l) to LDS
        if (par) {
            for (int m = 0; m < 2; ++m)
                for (int fn = 0; fn < 4; ++fn)
                    *(f32x4*)&Oex[hf][fn * 16 + ln][m * 16 + 4 * g] = o[m][fn];
            if (ln == 0)
                for (int m = 0; m < 2; ++m)
                    for (int r = 0; r < 4; ++r) {
                        Mex[hf][m * 16 + 4 * g + r] = mr[m][r];
                        Lex[hf][m * 16 + 4 * g + r] = lp[m][r];
                    }
        }
        __syncthreads();

        // even wave merges the two partials and writes y
        if (!par) {
            for (int m = 0; m < 2; ++m) {
                float a0[4], sc1[4], li[4];
                for (int r = 0; r < 4; ++r) {
                    int row = m * 16 + 4 * g + r;
                    float mo = Mex[hf][row], lo = Lex[hf][row];
                    float Mx = fmaxf(mr[m][r], mo);
                    a0[r] = exp2f(mr[m][r] - Mx);
                    sc1[r] = exp2f(mo - Mx);
                    li[r] = 1.0f / (lp[m][r] * a0[r] + lo * sc1[r]);
                }
                for (int fn = 0; fn < 4; ++fn) {
                    f32x4 Oo = *(const f32x4*)&Oex[hf][fn * 16 + ln][m * 16 + 4 * g];
                    for (int r = 0; r < 4; ++r) {
                        int row = qrow0 + m * 16 + 4 * g + r;
                        float val = (o[m][fn][r] * a0[r] + Oo[r] * sc1[r]) * li[r];
                        y[((size_t)b * T + row) * C + h * 64 + fn * 16 + ln] = f2b(val);
                    }
                }
            }
        }
        __syncthreads();   // protect exchange buffers before next pass overwrites
    }
}

extern "C" void kernel_launch(void* const* d_in, const int* in_sizes, int n_in,
                              void* d_out, int out_size, void* d_ws, size_t ws_size,
                              hipStream_t stream) {
    const float* hs    = (const float*)d_in[0];
    const float* basis = (const float*)d_in[1];
    const float* core  = (const float*)d_in[2];
    const float* resid = (const float*)d_in[3];
    const float* v_w   = (const float*)d_in[4];
    const float* v_b   = (const float*)d_in[5];
    const float* o_w   = (const float*)d_in[6];
    const float* o_b   = (const float*)d_in[7];
    float* out = (float*)d_out;

    const int B = 4, T = 2048, C = 1024, H = N_HEAD, R = RANK;
    const int M = B * T;  // 8192

    char* ws = (char*)d_ws;
    ushort* hs_b    = (ushort*)(ws + 0);         // 16,777,216 B
    ushort* y_b     = hs_b;                      // alias: hs dead after v-gemm
    ushort* basis_b = (ushort*)(ws + 16777216);  // 131,072
    ushort* vw_b    = (ushort*)(ws + 16908288);  // 2,097,152
    ushort* ow_b    = (ushort*)(ws + 19005440);  // 2,097,152
    ushort* hm_b    = (ushort*)(ws + 21102592);  // 131,072
    ushort* lat_b   = (ushort*)(ws + 21233664);  // 1,048,576
    ushort* lt_b    = (ushort*)(ws + 22282240);  // 16,777,216
    ushort* vT_b    = (ushort*)(ws + 39059456);  // 16,777,216  [B,H,64,T]

    // 1. convert inputs to bf16
    cvt_kernel<<<dim3(M * C / 4 / 256), 256, 0, stream>>>(hs, hs_b, M * C / 4);
    cvt_kernel<<<dim3(R * C / 4 / 256), 256, 0, stream>>>(basis, basis_b, R * C / 4);
    cvt_kernel<<<dim3(C * C / 4 / 256), 256, 0, stream>>>(v_w, vw_b, C * C / 4);
    cvt_kernel<<<dim3(C * C / 4 / 256), 256, 0, stream>>>(o_w, ow_b, C * C / 4);

    // 2. head matrices (transposed, pre-scaled, bf16)
    headmats_kernel<<<dim3(16), 256, 0, stream>>>(core, resid, hm_b);

    // 3. latent = hs @ basis^T : [8192,64]
    gemm_nt<64><<<dim3(1, M / 128, 1), 256, 0, stream>>>(
        hs_b, basis_b, nullptr, nullptr, lat_b, M, R, C, 1, 0, 1, 0, 0, 0);

    // 4. vT = (hs @ v_w^T + v_b)^T : [B,H,64,T] bf16, 128x128 tile
    gemm_nt<128><<<dim3(C / 128, M / 128, 1), 256, 0, stream>>>(
        hs_b, vw_b, v_b, nullptr, vT_b, M, C, C, 1, 0, 1, 0, 0, 1);

    // 5. lt[b,h] = latent[b] @ hmT[h]^T : batched z = b*H+h (pre-scaled)
    gemm_nt<64><<<dim3(1, T / 128, B * H), 256, 0, stream>>>(
        lat_b, hm_b, nullptr, nullptr, lt_b, T, R, R,
        H, (long long)T * R, H, (long long)R * R, (long long)T * R, 0);

    // 6. flash attention v4b -> y bf16 [B,T,C]
    attn_kernel<<<dim3(8, H, B), 512, 0, stream>>>(lt_b, lat_b, vT_b, y_b);

    // 7. out = y @ o_w^T + o_b : f32, 128x128 tile
    gemm_nt<128><<<dim3(C / 128, M / 128, 1), 256, 0, stream>>>(
        y_b, ow_b, o_b, out, nullptr, M, C, C, 1, 0, 1, 0, 0, 0);
}